// Round 14
// baseline (155.615 us; speedup 1.0000x reference)
//
#include <hip/hip_runtime.h>
#include <hip/hip_fp16.h>

#define Bsz 256
#define Nn  1152
#define Kk  10
#define NT  384      // 6 waves/block
#define NW  6
#define S4  1156     // uint stride per o-pair row (R8-verified layout)

#define W_ELEMS (Kk*Nn*128)     // 1474560
#define U_ELEMS (Bsz*Nn*8)      // 2359296

typedef _Float16 hf2_t __attribute__((ext_vector_type(2)));

static __device__ __forceinline__ unsigned pkh2(float x, float y) {
    __half2 h = __floats2half2_rn(x, y);
    return *reinterpret_cast<unsigned*>(&h);
}
// v_dot2_f32_f16: c += a.lo*b.lo + a.hi*b.hi (f32 accumulate, 1 inst)
static __device__ __forceinline__ float fdot2u(unsigned a, unsigned b, float c) {
    union { unsigned u; hf2_t h; } A, B;
    A.u = a; B.u = b;
    return __builtin_amdgcn_fdot2(A.h, B.h, c, false);
}
// Within-wave LDS write->read ordering (no s_barrier for wave-local data)
static __device__ __forceinline__ void wave_lds_fence() {
    __builtin_amdgcn_sched_barrier(0);
    asm volatile("s_waitcnt lgkmcnt(0)" ::: "memory");
    __builtin_amdgcn_sched_barrier(0);
}

#define PERM_LO 0x01000504u   // perm(a,b,LO) = half2(lo = lo16(a), hi = lo16(b))
#define PERM_HI 0x03020706u
#define ONE2    0x3C003C00u   // half2(1, 1)

// Simple elementwise fp32->fp16 of W then u (8 elems/thread), layouts unchanged.
__global__ void cvt_kernel(const float* __restrict__ W, const float* __restrict__ u,
                           __half2* __restrict__ Wh, __half2* __restrict__ uh) {
    const int idx = blockIdx.x * blockDim.x + threadIdx.x;
    const int wg = W_ELEMS / 8;            // 184320
    const float4* p;
    __half2* o;
    if (idx < wg) {
        p = (const float4*)W + (size_t)idx * 2;
        o = Wh + (size_t)idx * 4;
    } else {
        const int j = idx - wg;            // < 294912
        p = (const float4*)u + (size_t)j * 2;
        o = uh + (size_t)j * 4;
    }
    const float4 a = p[0], b = p[1];
    o[0] = __floats2half2_rn(a.x, a.y);
    o[1] = __floats2half2_rn(a.z, a.w);
    o[2] = __floats2half2_rn(b.x, b.y);
    o[3] = __floats2half2_rn(b.z, b.w);
}

// One block per (b-pair, k): b0 (u_hat in LDS, R8 routing), b1 (u_hat in 24 regs,
// R12 routing). Phase 1 loads each W cell ONCE for both b's (R13-verified).
// ROUND-14: __launch_bounds__(384,5) -> VGPR cap 102 (3 blocks/CU = 18 waves),
// plus sched_barrier(0) at each phase-1 iteration boundary to stop the scheduler
// hoisting loads across iterations (R13's 30 MB spill driver). WRITE_SIZE is the
// spill tripwire.
template<bool HALF>
__global__ __launch_bounds__(NT, 5)
void digitcaps_kernel(const float* __restrict__ u32, const float* __restrict__ W32,
                      const __half* __restrict__ uh, const __half* __restrict__ Wh,
                      float* __restrict__ out)
{
    const int t    = threadIdx.x;
    const int lane = t & 63;
    const int wav  = t >> 6;
    const int oh   = lane & 1;
    const int pr   = lane >> 1;          // 0..31
    const int bg   = blockIdx.x;         // 0..127
    const int k    = blockIdx.y;         // 0..9
    const int b0   = 2 * bg;
    const int b1   = 2 * bg + 1;

    __shared__ unsigned uhS[8 * S4];        // 36992 B  b0 u_hat: row j = o-pair, col n
    __shared__ unsigned cS2u[Nn / 2];       // 2304 B   b0 e per n (half), uint-paired
    __shared__ float    redS[2][2][NW][20]; // 1920 B   [buf][b][wav][s0..15, d, m_w, pad2]
    // total 41216 B -> 3 blocks/CU (LDS-limited); VGPR <= 102 keeps 18 waves/CU

    unsigned uh_r[6][4];    // b1 u_hat: [rr][jj] = half2(o=8oh+2jj, +1) for n=192rr+32wav+pr

    // ---------------- Phase 1: u_hat = u . W for BOTH b's, W loaded once ----------------
    #pragma unroll
    for (int rr = 0; rr < 6; ++rr) {
        const int n = 192 * rr + 32 * wav + pr;
        float a0[8], a1[8];
        #pragma unroll
        for (int o = 0; o < 8; ++o) { a0[o] = 0.f; a1[o] = 0.f; }
        if (HALF) {
            const uint4 uq0 = *(const uint4*)(uh + ((size_t)b0 * Nn + n) * 8);
            const uint4 uq1 = *(const uint4*)(uh + ((size_t)b1 * Nn + n) * 8);
            const unsigned uw0[4] = {uq0.x, uq0.y, uq0.z, uq0.w};
            const unsigned uw1[4] = {uq1.x, uq1.y, uq1.z, uq1.w};
            const __half* wbase = Wh + ((size_t)(k * Nn + n)) * 128 + oh * 8;
            #pragma unroll
            for (int p = 0; p < 4; ++p) {
                const uint4 qa = *(const uint4*)(wbase + (2 * p    ) * 16);
                const uint4 qb = *(const uint4*)(wbase + (2 * p + 1) * 16);
                const unsigned aw[4] = {qa.x, qa.y, qa.z, qa.w};
                const unsigned bw[4] = {qb.x, qb.y, qb.z, qb.w};
                #pragma unroll
                for (int jj = 0; jj < 4; ++jj) {
                    const unsigned wl  = __builtin_amdgcn_perm(aw[jj], bw[jj], PERM_LO);
                    const unsigned wh2 = __builtin_amdgcn_perm(aw[jj], bw[jj], PERM_HI);
                    a0[2*jj]   = fdot2u(wl,  uw0[p], a0[2*jj]);
                    a0[2*jj+1] = fdot2u(wh2, uw0[p], a0[2*jj+1]);
                    a1[2*jj]   = fdot2u(wl,  uw1[p], a1[2*jj]);
                    a1[2*jj+1] = fdot2u(wh2, uw1[p], a1[2*jj+1]);
                }
            }
        } else {
            float ua0[8], ua1[8];
            const float4* up0 = (const float4*)(u32 + ((size_t)b0 * Nn + n) * 8);
            const float4* up1 = (const float4*)(u32 + ((size_t)b1 * Nn + n) * 8);
            const float4 x0 = up0[0], x1 = up0[1];
            const float4 y0 = up1[0], y1 = up1[1];
            ua0[0]=x0.x; ua0[1]=x0.y; ua0[2]=x0.z; ua0[3]=x0.w;
            ua0[4]=x1.x; ua0[5]=x1.y; ua0[6]=x1.z; ua0[7]=x1.w;
            ua1[0]=y0.x; ua1[1]=y0.y; ua1[2]=y0.z; ua1[3]=y0.w;
            ua1[4]=y1.x; ua1[5]=y1.y; ua1[6]=y1.z; ua1[7]=y1.w;
            #pragma unroll
            for (int i = 0; i < 8; ++i) {
                const float4* wp = (const float4*)(W32 + ((size_t)k * Nn + n) * 128) + oh * 2 + i * 4;
                const float4 w0 = wp[0], w1 = wp[1];
                float wv[8];
                wv[0]=w0.x; wv[1]=w0.y; wv[2]=w0.z; wv[3]=w0.w;
                wv[4]=w1.x; wv[5]=w1.y; wv[6]=w1.z; wv[7]=w1.w;
                const float x = ua0[i], y = ua1[i];
                #pragma unroll
                for (int o = 0; o < 8; ++o) { a0[o] += x * wv[o]; a1[o] += y * wv[o]; }
            }
        }
        #pragma unroll
        for (int jj = 0; jj < 4; ++jj) {
            uhS[(oh * 4 + jj) * S4 + n] = pkh2(a0[2*jj], a0[2*jj+1]);
            uh_r[rr][jj] = pkh2(a1[2*jj], a1[2*jj+1]);
        }
        // Pin iteration boundary: no cross-iteration load hoisting (spill control).
        __builtin_amdgcn_sched_barrier(0);
    }
    wave_lds_fence();   // all later uhS/cS consumption is wave-local

    // ---------------- Phase 2: routing ----------------
    float lg0[3] = {0.f, 0.f, 0.f};                         // b0 (LDS rows)
    float lg1[6] = {0.f, 0.f, 0.f, 0.f, 0.f, 0.f};          // b1 (reg rows)
    unsigned vh0[8];    // full v_b0 (b0 a-scan reads all 16 o from LDS)
    unsigned vo1[4];    // own oh-half of v_b1
    const int j_s = lane & 7;
    const int g_s = lane >> 3;
    const int l5  = lane >> 5;
    const int l31 = lane & 31;

    #pragma unroll
    for (int it = 0; it < 3; ++it) {
        float m0 = 0.f, m1 = 0.f;
        float c1[6];
        if (it > 0) {
            // ---- b0 a-scan (R8): own LDS columns n = 384j + 192 l5 + 32 wav + l31 ----
            #pragma unroll
            for (int j = 0; j < 3; ++j) {
                const int n = 384 * j + 192 * l5 + 32 * wav + l31;
                float acc = 0.f;
                #pragma unroll
                for (int jj = 0; jj < 8; ++jj)
                    acc = fdot2u(uhS[jj * S4 + n], vh0[jj], acc);
                lg0[j] += acc;
            }
            // ---- b1 a-scan (R12): own regs + oh-partner shfl ----
            #pragma unroll
            for (int rr = 0; rr < 6; ++rr) {
                float acc = 0.f;
                #pragma unroll
                for (int jj = 0; jj < 4; ++jj)
                    acc = fdot2u(uh_r[rr][jj], vo1[jj], acc);
                lg1[rr] += acc + __shfl_xor(acc, 1);
            }
            // ---- per-wave maxes ----
            m0 = fmaxf(fmaxf(lg0[0], lg0[1]), lg0[2]);
            m1 = fmaxf(fmaxf(fmaxf(lg1[0], lg1[1]), fmaxf(lg1[2], lg1[3])),
                       fmaxf(lg1[4], lg1[5]));
            #pragma unroll
            for (int off = 1; off <= 32; off <<= 1) {
                m0 = fmaxf(m0, __shfl_xor(m0, off));
                m1 = fmaxf(m1, __shfl_xor(m1, off));
            }
            // ---- b0 e -> LDS (half per n); b1 c -> regs ----
            #pragma unroll
            for (int j = 0; j < 3; ++j) {
                const int n = 384 * j + 192 * l5 + 32 * wav + l31;
                ((__half*)cS2u)[n] = __float2half(__expf(lg0[j] - m0));
            }
            #pragma unroll
            for (int rr = 0; rr < 6; ++rr) c1[rr] = __expf(lg1[rr] - m1);
            wave_lds_fence();   // cS readers are this same wave
        } else {
            #pragma unroll
            for (int rr = 0; rr < 6; ++rr) c1[rr] = 1.f;
        }

        // ---- b0 s-scan (R8): LDS pairs (n0, n0+1) ----
        float2 sp0 = {0.f, 0.f};
        float dp0 = 0.f;
        #pragma unroll
        for (int cc = 0; cc < 12; ++cc) {
            const int P  = g_s + 8 * cc;
            const int n0 = 192 * (P >> 4) + 32 * wav + 2 * (P & 15);
            const unsigned cp = (it == 0) ? ONE2 : cS2u[n0 >> 1];
            const uint2 q = *(const uint2*)&uhS[j_s * S4 + n0];
            const unsigned px = __builtin_amdgcn_perm(q.x, q.y, PERM_LO);
            const unsigned py = __builtin_amdgcn_perm(q.x, q.y, PERM_HI);
            sp0.x = fdot2u(px, cp, sp0.x);
            sp0.y = fdot2u(py, cp, sp0.y);
            dp0   = fdot2u(cp, ONE2, dp0);
        }
        #pragma unroll
        for (int off = 8; off <= 32; off <<= 1) {
            sp0.x += __shfl_xor(sp0.x, off);
            sp0.y += __shfl_xor(sp0.y, off);
            dp0   += __shfl_xor(dp0,   off);
        }

        // ---- b1 s-scan (R12): in-register row-pair perm + dot2 ----
        float sp1[8] = {0.f, 0.f, 0.f, 0.f, 0.f, 0.f, 0.f, 0.f};
        float dp1 = 0.f;
        #pragma unroll
        for (int q2 = 0; q2 < 3; ++q2) {
            const unsigned cp1 = pkh2(c1[2*q2], c1[2*q2+1]);
            dp1 = fdot2u(cp1, ONE2, dp1);
            #pragma unroll
            for (int jj = 0; jj < 4; ++jj) {
                const unsigned px = __builtin_amdgcn_perm(uh_r[2*q2][jj], uh_r[2*q2+1][jj], PERM_LO);
                const unsigned py = __builtin_amdgcn_perm(uh_r[2*q2][jj], uh_r[2*q2+1][jj], PERM_HI);
                sp1[2*jj]   = fdot2u(px, cp1, sp1[2*jj]);
                sp1[2*jj+1] = fdot2u(py, cp1, sp1[2*jj+1]);
            }
        }
        #pragma unroll
        for (int off = 2; off <= 32; off <<= 1) {     // keep oh groups separate
            #pragma unroll
            for (int e = 0; e < 8; ++e) sp1[e] += __shfl_xor(sp1[e], off);
            dp1 += __shfl_xor(dp1, off);
        }

        const int buf = it & 1;
        if (lane < 8) {
            redS[buf][0][wav][2 * j_s    ] = sp0.x;
            redS[buf][0][wav][2 * j_s + 1] = sp0.y;
        }
        if (lane < 2) {      // lane == oh; lane0 -> s[0..7], lane1 -> s[8..15]
            float2* dst = (float2*)&redS[buf][1][wav][8 * lane];
            dst[0] = make_float2(sp1[0], sp1[1]);
            dst[1] = make_float2(sp1[2], sp1[3]);
            dst[2] = make_float2(sp1[4], sp1[5]);
            dst[3] = make_float2(sp1[6], sp1[7]);
        }
        if (lane == 0) {
            *(float2*)&redS[buf][0][wav][16] = make_float2(dp0, m0);
            *(float2*)&redS[buf][1][wav][16] = make_float2(dp1, m1);
        }
        __syncthreads();                               // the ONLY barrier per iter

        // ---- finalize: per-b cross-wave rescale + squash; b = (lane>>4)&1 ----
        if (it < 2 || wav == 0) {
            const int bsel = (lane >> 4) & 1;
            const int o    = lane & 15;
            float M = redS[buf][bsel][0][17];
            #pragma unroll
            for (int w = 1; w < NW; ++w) M = fmaxf(M, redS[buf][bsel][w][17]);
            float s = 0.f, d = 0.f;
            #pragma unroll
            for (int w = 0; w < NW; ++w) {
                const float2 dm = *(const float2*)&redS[buf][bsel][w][16];
                const float sc = (it == 0) ? 1.f : __expf(dm.y - M);
                s += sc * redS[buf][bsel][w][o];
                d += sc * dm.x;
            }
            s /= d;
            float s2 = s * s;
            #pragma unroll
            for (int off = 1; off <= 8; off <<= 1) s2 += __shfl_xor(s2, off);
            const float scale = (s2 / (1.f + s2)) * rsqrtf(fmaxf(s2, 1e-30f));
            const float v = s * scale;
            if (it == 2) {
                if (wav == 0 && lane < 32)
                    out[((size_t)k * Bsz + b0 + bsel) * 16 + o] = v;
            } else {
                // v_b0 lives in lanes 0-15, v_b1 in lanes 16-31 (static subscripts only)
                #pragma unroll
                for (int jj = 0; jj < 8; ++jj)
                    vh0[jj] = pkh2(__shfl(v, 2 * jj), __shfl(v, 2 * jj + 1));
                #pragma unroll
                for (int jj = 0; jj < 4; ++jj)
                    vo1[jj] = pkh2(__shfl(v, 16 + 8 * oh + 2 * jj),
                                   __shfl(v, 16 + 8 * oh + 2 * jj + 1));
            }
        }
    }
}

extern "C" void kernel_launch(void* const* d_in, const int* in_sizes, int n_in,
                              void* d_out, int out_size, void* d_ws, size_t ws_size,
                              hipStream_t stream) {
    const float* u = (const float*)d_in[0];
    const float* W = (const float*)d_in[1];
    float* out = (float*)d_out;
    const size_t need = (size_t)(W_ELEMS + U_ELEMS) * sizeof(__half);
    if (ws_size >= need) {
        __half* Wh = (__half*)d_ws;
        __half* uh = (__half*)((char*)d_ws + (size_t)W_ELEMS * sizeof(__half));
        cvt_kernel<<<dim3((W_ELEMS + U_ELEMS) / 8 / 256), dim3(256), 0, stream>>>(
            W, u, (__half2*)Wh, (__half2*)uh);
        digitcaps_kernel<true><<<dim3(128, 10), dim3(NT), 0, stream>>>(
            nullptr, nullptr, uh, Wh, out);
    } else {
        digitcaps_kernel<false><<<dim3(128, 10), dim3(NT), 0, stream>>>(
            u, W, nullptr, nullptr, out);
    }
}

// Round 15
// 128.228 us; speedup vs baseline: 1.2136x; 1.2136x over previous
//
#include <hip/hip_runtime.h>
#include <hip/hip_fp16.h>

#define Bsz 256
#define Nn  1152
#define Kk  10
#define NT  384      // 6 waves/block
#define NW  6
#define S4  1156     // uint stride per o-pair row (R8-verified layout)

#define W_ELEMS (Kk*Nn*128)     // 1474560
#define U_ELEMS (Bsz*Nn*8)      // 2359296

typedef _Float16 hf2_t __attribute__((ext_vector_type(2)));

static __device__ __forceinline__ unsigned pkh2(float x, float y) {
    __half2 h = __floats2half2_rn(x, y);
    return *reinterpret_cast<unsigned*>(&h);
}
// v_dot2_f32_f16: c += a.lo*b.lo + a.hi*b.hi (f32 accumulate, 1 inst)
static __device__ __forceinline__ float fdot2u(unsigned a, unsigned b, float c) {
    union { unsigned u; hf2_t h; } A, B;
    A.u = a; B.u = b;
    return __builtin_amdgcn_fdot2(A.h, B.h, c, false);
}
// Within-wave LDS write->read ordering (no s_barrier for wave-local data)
static __device__ __forceinline__ void wave_lds_fence() {
    __builtin_amdgcn_sched_barrier(0);
    asm volatile("s_waitcnt lgkmcnt(0)" ::: "memory");
    __builtin_amdgcn_sched_barrier(0);
}

#define PERM_LO 0x01000504u   // perm(a,b,LO) = half2(lo = lo16(a), hi = lo16(b))
#define PERM_HI 0x03020706u
#define ONE2    0x3C003C00u   // half2(1, 1)

// Simple elementwise fp32->fp16 of W then u (8 elems/thread), layouts unchanged.
__global__ void cvt_kernel(const float* __restrict__ W, const float* __restrict__ u,
                           __half2* __restrict__ Wh, __half2* __restrict__ uh) {
    const int idx = blockIdx.x * blockDim.x + threadIdx.x;
    const int wg = W_ELEMS / 8;            // 184320
    const float4* p;
    __half2* o;
    if (idx < wg) {
        p = (const float4*)W + (size_t)idx * 2;
        o = Wh + (size_t)idx * 4;
    } else {
        const int j = idx - wg;            // < 294912
        p = (const float4*)u + (size_t)j * 2;
        o = uh + (size_t)j * 4;
    }
    const float4 a = p[0], b = p[1];
    o[0] = __floats2half2_rn(a.x, a.y);
    o[1] = __floats2half2_rn(a.z, a.w);
    o[2] = __floats2half2_rn(b.x, b.y);
    o[3] = __floats2half2_rn(b.z, b.w);
}

// One block per (b-pair, k): b0 (u_hat in LDS, R8 routing), b1 (u_hat in 24 regs,
// R12 routing). Phase 1 loads each W cell ONCE for both b's (R13-verified, best
// known: 64.5 us with 30 MB spill at cap 128).
// ROUND-15: __launch_bounds__(384,3) -> VGPR cap ~170, fits the ~140 live regs
// spill-free at the SAME effective occupancy R13 ran (2 blocks/CU). R14's tighter
// cap (102) tripled the spill — allocation is liveness, not scheduling.
// WRITE_SIZE is the spill tripwire: clean run must show ~0.2 MB.
template<bool HALF>
__global__ __launch_bounds__(NT, 3)
void digitcaps_kernel(const float* __restrict__ u32, const float* __restrict__ W32,
                      const __half* __restrict__ uh, const __half* __restrict__ Wh,
                      float* __restrict__ out)
{
    const int t    = threadIdx.x;
    const int lane = t & 63;
    const int wav  = t >> 6;
    const int oh   = lane & 1;
    const int pr   = lane >> 1;          // 0..31
    const int bg   = blockIdx.x;         // 0..127
    const int k    = blockIdx.y;         // 0..9
    const int b0   = 2 * bg;
    const int b1   = 2 * bg + 1;

    __shared__ unsigned uhS[8 * S4];        // 36992 B  b0 u_hat: row j = o-pair, col n
    __shared__ unsigned cS2u[Nn / 2];       // 2304 B   b0 e per n (half), uint-paired
    __shared__ float    redS[2][2][NW][20]; // 1920 B   [buf][b][wav][s0..15, d, m_w, pad2]
    // total 41216 B; VGPR ~140 -> 2 blocks/CU (12 waves), same as R13 measured

    unsigned uh_r[6][4];    // b1 u_hat: [rr][jj] = half2(o=8oh+2jj, +1) for n=192rr+32wav+pr

    // ---------------- Phase 1: u_hat = u . W for BOTH b's, W loaded once ----------------
    #pragma unroll
    for (int rr = 0; rr < 6; ++rr) {
        const int n = 192 * rr + 32 * wav + pr;
        float a0[8], a1[8];
        #pragma unroll
        for (int o = 0; o < 8; ++o) { a0[o] = 0.f; a1[o] = 0.f; }
        if (HALF) {
            const uint4 uq0 = *(const uint4*)(uh + ((size_t)b0 * Nn + n) * 8);
            const uint4 uq1 = *(const uint4*)(uh + ((size_t)b1 * Nn + n) * 8);
            const unsigned uw0[4] = {uq0.x, uq0.y, uq0.z, uq0.w};
            const unsigned uw1[4] = {uq1.x, uq1.y, uq1.z, uq1.w};
            const __half* wbase = Wh + ((size_t)(k * Nn + n)) * 128 + oh * 8;
            #pragma unroll
            for (int p = 0; p < 4; ++p) {
                const uint4 qa = *(const uint4*)(wbase + (2 * p    ) * 16);
                const uint4 qb = *(const uint4*)(wbase + (2 * p + 1) * 16);
                const unsigned aw[4] = {qa.x, qa.y, qa.z, qa.w};
                const unsigned bw[4] = {qb.x, qb.y, qb.z, qb.w};
                #pragma unroll
                for (int jj = 0; jj < 4; ++jj) {
                    const unsigned wl  = __builtin_amdgcn_perm(aw[jj], bw[jj], PERM_LO);
                    const unsigned wh2 = __builtin_amdgcn_perm(aw[jj], bw[jj], PERM_HI);
                    a0[2*jj]   = fdot2u(wl,  uw0[p], a0[2*jj]);
                    a0[2*jj+1] = fdot2u(wh2, uw0[p], a0[2*jj+1]);
                    a1[2*jj]   = fdot2u(wl,  uw1[p], a1[2*jj]);
                    a1[2*jj+1] = fdot2u(wh2, uw1[p], a1[2*jj+1]);
                }
            }
        } else {
            float ua0[8], ua1[8];
            const float4* up0 = (const float4*)(u32 + ((size_t)b0 * Nn + n) * 8);
            const float4* up1 = (const float4*)(u32 + ((size_t)b1 * Nn + n) * 8);
            const float4 x0 = up0[0], x1 = up0[1];
            const float4 y0 = up1[0], y1 = up1[1];
            ua0[0]=x0.x; ua0[1]=x0.y; ua0[2]=x0.z; ua0[3]=x0.w;
            ua0[4]=x1.x; ua0[5]=x1.y; ua0[6]=x1.z; ua0[7]=x1.w;
            ua1[0]=y0.x; ua1[1]=y0.y; ua1[2]=y0.z; ua1[3]=y0.w;
            ua1[4]=y1.x; ua1[5]=y1.y; ua1[6]=y1.z; ua1[7]=y1.w;
            #pragma unroll
            for (int i = 0; i < 8; ++i) {
                const float4* wp = (const float4*)(W32 + ((size_t)k * Nn + n) * 128) + oh * 2 + i * 4;
                const float4 w0 = wp[0], w1 = wp[1];
                float wv[8];
                wv[0]=w0.x; wv[1]=w0.y; wv[2]=w0.z; wv[3]=w0.w;
                wv[4]=w1.x; wv[5]=w1.y; wv[6]=w1.z; wv[7]=w1.w;
                const float x = ua0[i], y = ua1[i];
                #pragma unroll
                for (int o = 0; o < 8; ++o) { a0[o] += x * wv[o]; a1[o] += y * wv[o]; }
            }
        }
        #pragma unroll
        for (int jj = 0; jj < 4; ++jj) {
            uhS[(oh * 4 + jj) * S4 + n] = pkh2(a0[2*jj], a0[2*jj+1]);
            uh_r[rr][jj] = pkh2(a1[2*jj], a1[2*jj+1]);
        }
    }
    wave_lds_fence();   // all later uhS/cS consumption is wave-local

    // ---------------- Phase 2: routing ----------------
    float lg0[3] = {0.f, 0.f, 0.f};                         // b0 (LDS rows)
    float lg1[6] = {0.f, 0.f, 0.f, 0.f, 0.f, 0.f};          // b1 (reg rows)
    unsigned vh0[8];    // full v_b0 (b0 a-scan reads all 16 o from LDS)
    unsigned vo1[4];    // own oh-half of v_b1
    const int j_s = lane & 7;
    const int g_s = lane >> 3;
    const int l5  = lane >> 5;
    const int l31 = lane & 31;

    #pragma unroll
    for (int it = 0; it < 3; ++it) {
        float m0 = 0.f, m1 = 0.f;
        float c1[6];
        if (it > 0) {
            // ---- b0 a-scan (R8): own LDS columns n = 384j + 192 l5 + 32 wav + l31 ----
            #pragma unroll
            for (int j = 0; j < 3; ++j) {
                const int n = 384 * j + 192 * l5 + 32 * wav + l31;
                float acc = 0.f;
                #pragma unroll
                for (int jj = 0; jj < 8; ++jj)
                    acc = fdot2u(uhS[jj * S4 + n], vh0[jj], acc);
                lg0[j] += acc;
            }
            // ---- b1 a-scan (R12): own regs + oh-partner shfl ----
            #pragma unroll
            for (int rr = 0; rr < 6; ++rr) {
                float acc = 0.f;
                #pragma unroll
                for (int jj = 0; jj < 4; ++jj)
                    acc = fdot2u(uh_r[rr][jj], vo1[jj], acc);
                lg1[rr] += acc + __shfl_xor(acc, 1);
            }
            // ---- per-wave maxes ----
            m0 = fmaxf(fmaxf(lg0[0], lg0[1]), lg0[2]);
            m1 = fmaxf(fmaxf(fmaxf(lg1[0], lg1[1]), fmaxf(lg1[2], lg1[3])),
                       fmaxf(lg1[4], lg1[5]));
            #pragma unroll
            for (int off = 1; off <= 32; off <<= 1) {
                m0 = fmaxf(m0, __shfl_xor(m0, off));
                m1 = fmaxf(m1, __shfl_xor(m1, off));
            }
            // ---- b0 e -> LDS (half per n); b1 c -> regs ----
            #pragma unroll
            for (int j = 0; j < 3; ++j) {
                const int n = 384 * j + 192 * l5 + 32 * wav + l31;
                ((__half*)cS2u)[n] = __float2half(__expf(lg0[j] - m0));
            }
            #pragma unroll
            for (int rr = 0; rr < 6; ++rr) c1[rr] = __expf(lg1[rr] - m1);
            wave_lds_fence();   // cS readers are this same wave
        } else {
            #pragma unroll
            for (int rr = 0; rr < 6; ++rr) c1[rr] = 1.f;
        }

        // ---- b0 s-scan (R8): LDS pairs (n0, n0+1) ----
        float2 sp0 = {0.f, 0.f};
        float dp0 = 0.f;
        #pragma unroll
        for (int cc = 0; cc < 12; ++cc) {
            const int P  = g_s + 8 * cc;
            const int n0 = 192 * (P >> 4) + 32 * wav + 2 * (P & 15);
            const unsigned cp = (it == 0) ? ONE2 : cS2u[n0 >> 1];
            const uint2 q = *(const uint2*)&uhS[j_s * S4 + n0];
            const unsigned px = __builtin_amdgcn_perm(q.x, q.y, PERM_LO);
            const unsigned py = __builtin_amdgcn_perm(q.x, q.y, PERM_HI);
            sp0.x = fdot2u(px, cp, sp0.x);
            sp0.y = fdot2u(py, cp, sp0.y);
            dp0   = fdot2u(cp, ONE2, dp0);
        }
        #pragma unroll
        for (int off = 8; off <= 32; off <<= 1) {
            sp0.x += __shfl_xor(sp0.x, off);
            sp0.y += __shfl_xor(sp0.y, off);
            dp0   += __shfl_xor(dp0,   off);
        }

        // ---- b1 s-scan (R12): in-register row-pair perm + dot2 ----
        float sp1[8] = {0.f, 0.f, 0.f, 0.f, 0.f, 0.f, 0.f, 0.f};
        float dp1 = 0.f;
        #pragma unroll
        for (int q2 = 0; q2 < 3; ++q2) {
            const unsigned cp1 = pkh2(c1[2*q2], c1[2*q2+1]);
            dp1 = fdot2u(cp1, ONE2, dp1);
            #pragma unroll
            for (int jj = 0; jj < 4; ++jj) {
                const unsigned px = __builtin_amdgcn_perm(uh_r[2*q2][jj], uh_r[2*q2+1][jj], PERM_LO);
                const unsigned py = __builtin_amdgcn_perm(uh_r[2*q2][jj], uh_r[2*q2+1][jj], PERM_HI);
                sp1[2*jj]   = fdot2u(px, cp1, sp1[2*jj]);
                sp1[2*jj+1] = fdot2u(py, cp1, sp1[2*jj+1]);
            }
        }
        #pragma unroll
        for (int off = 2; off <= 32; off <<= 1) {     // keep oh groups separate
            #pragma unroll
            for (int e = 0; e < 8; ++e) sp1[e] += __shfl_xor(sp1[e], off);
            dp1 += __shfl_xor(dp1, off);
        }

        const int buf = it & 1;
        if (lane < 8) {
            redS[buf][0][wav][2 * j_s    ] = sp0.x;
            redS[buf][0][wav][2 * j_s + 1] = sp0.y;
        }
        if (lane < 2) {      // lane == oh; lane0 -> s[0..7], lane1 -> s[8..15]
            float2* dst = (float2*)&redS[buf][1][wav][8 * lane];
            dst[0] = make_float2(sp1[0], sp1[1]);
            dst[1] = make_float2(sp1[2], sp1[3]);
            dst[2] = make_float2(sp1[4], sp1[5]);
            dst[3] = make_float2(sp1[6], sp1[7]);
        }
        if (lane == 0) {
            *(float2*)&redS[buf][0][wav][16] = make_float2(dp0, m0);
            *(float2*)&redS[buf][1][wav][16] = make_float2(dp1, m1);
        }
        __syncthreads();                               // the ONLY barrier per iter

        // ---- finalize: per-b cross-wave rescale + squash; b = (lane>>4)&1 ----
        if (it < 2 || wav == 0) {
            const int bsel = (lane >> 4) & 1;
            const int o    = lane & 15;
            float M = redS[buf][bsel][0][17];
            #pragma unroll
            for (int w = 1; w < NW; ++w) M = fmaxf(M, redS[buf][bsel][w][17]);
            float s = 0.f, d = 0.f;
            #pragma unroll
            for (int w = 0; w < NW; ++w) {
                const float2 dm = *(const float2*)&redS[buf][bsel][w][16];
                const float sc = (it == 0) ? 1.f : __expf(dm.y - M);
                s += sc * redS[buf][bsel][w][o];
                d += sc * dm.x;
            }
            s /= d;
            float s2 = s * s;
            #pragma unroll
            for (int off = 1; off <= 8; off <<= 1) s2 += __shfl_xor(s2, off);
            const float scale = (s2 / (1.f + s2)) * rsqrtf(fmaxf(s2, 1e-30f));
            const float v = s * scale;
            if (it == 2) {
                if (wav == 0 && lane < 32)
                    out[((size_t)k * Bsz + b0 + bsel) * 16 + o] = v;
            } else {
                // v_b0 lives in lanes 0-15, v_b1 in lanes 16-31 (static subscripts only)
                #pragma unroll
                for (int jj = 0; jj < 8; ++jj)
                    vh0[jj] = pkh2(__shfl(v, 2 * jj), __shfl(v, 2 * jj + 1));
                #pragma unroll
                for (int jj = 0; jj < 4; ++jj)
                    vo1[jj] = pkh2(__shfl(v, 16 + 8 * oh + 2 * jj),
                                   __shfl(v, 16 + 8 * oh + 2 * jj + 1));
            }
        }
    }
}

extern "C" void kernel_launch(void* const* d_in, const int* in_sizes, int n_in,
                              void* d_out, int out_size, void* d_ws, size_t ws_size,
                              hipStream_t stream) {
    const float* u = (const float*)d_in[0];
    const float* W = (const float*)d_in[1];
    float* out = (float*)d_out;
    const size_t need = (size_t)(W_ELEMS + U_ELEMS) * sizeof(__half);
    if (ws_size >= need) {
        __half* Wh = (__half*)d_ws;
        __half* uh = (__half*)((char*)d_ws + (size_t)W_ELEMS * sizeof(__half));
        cvt_kernel<<<dim3((W_ELEMS + U_ELEMS) / 8 / 256), dim3(256), 0, stream>>>(
            W, u, (__half2*)Wh, (__half2*)uh);
        digitcaps_kernel<true><<<dim3(128, 10), dim3(NT), 0, stream>>>(
            nullptr, nullptr, uh, Wh, out);
    } else {
        digitcaps_kernel<false><<<dim3(128, 10), dim3(NT), 0, stream>>>(
            u, W, nullptr, nullptr, out);
    }
}

// Round 16
// 115.029 us; speedup vs baseline: 1.3528x; 1.1147x over previous
//
#include <hip/hip_runtime.h>
#include <hip/hip_fp16.h>

#define Bsz 256
#define Nn  1152
#define Kk  10
#define NT  768      // 12 waves/block; LDS exactly 80 KB -> 2 blocks/CU = 24 waves
#define NW  12
#define S4  1154     // uint stride per o-pair row (mod 32 = 2; uint2-aligned)

#define W_ELEMS (Kk*Nn*128)     // 1474560
#define U_ELEMS (Bsz*Nn*8)      // 2359296

typedef _Float16 hf2_t __attribute__((ext_vector_type(2)));

static __device__ __forceinline__ unsigned pkh2(float x, float y) {
    __half2 h = __floats2half2_rn(x, y);
    return *reinterpret_cast<unsigned*>(&h);
}
// v_dot2_f32_f16: c += a.lo*b.lo + a.hi*b.hi (f32 accumulate, 1 inst)
static __device__ __forceinline__ float fdot2u(unsigned a, unsigned b, float c) {
    union { unsigned u; hf2_t h; } A, B;
    A.u = a; B.u = b;
    return __builtin_amdgcn_fdot2(A.h, B.h, c, false);
}
// Within-wave LDS write->read ordering (no s_barrier for wave-local data)
static __device__ __forceinline__ void wave_lds_fence() {
    __builtin_amdgcn_sched_barrier(0);
    asm volatile("s_waitcnt lgkmcnt(0)" ::: "memory");
    __builtin_amdgcn_sched_barrier(0);
}

#define PERM_LO 0x01000504u   // perm(a,b,LO) = half2(lo = lo16(a), hi = lo16(b))
#define PERM_HI 0x03020706u
#define ONE2    0x3C003C00u   // half2(1, 1)

// Simple elementwise fp32->fp16 of W then u (8 elems/thread), layouts unchanged.
__global__ void cvt_kernel(const float* __restrict__ W, const float* __restrict__ u,
                           __half2* __restrict__ Wh, __half2* __restrict__ uh) {
    const int idx = blockIdx.x * blockDim.x + threadIdx.x;
    const int wg = W_ELEMS / 8;            // 184320
    const float4* p;
    __half2* o;
    if (idx < wg) {
        p = (const float4*)W + (size_t)idx * 2;
        o = Wh + (size_t)idx * 4;
    } else {
        const int j = idx - wg;            // < 294912
        p = (const float4*)u + (size_t)j * 2;
        o = uh + (size_t)j * 4;
    }
    const float4 a = p[0], b = p[1];
    o[0] = __floats2half2_rn(a.x, a.y);
    o[1] = __floats2half2_rn(a.z, a.w);
    o[2] = __floats2half2_rn(b.x, b.y);
    o[3] = __floats2half2_rn(b.z, b.w);
}

// One block per (b-pair, k), 12 waves. Wave w owns rows n = 96w + 32rr + pr
// (pr = lane>>1, rr = 0..2). Phase 1 loads each W cell ONCE and produces u_hat
// for BOTH b's into LDS (R13's W-share without its register pressure).
// Routing: even lanes route b0, odd lanes b1 (oh-split a-scan; per-b wave max
// via parity-preserving shfl_xor offsets 2..32); s-scan covers both b's;
// cross-wave exp(m_w - M) rescale at finalize. 3 barriers + wave-local fences.
// Register state ~30 persistent (no uh_r/vh0) -> no spill at 6 waves/SIMD cap 85.
// WRITE_SIZE is the spill tripwire.
template<bool HALF>
__global__ __launch_bounds__(NT, 6)
void digitcaps_kernel(const float* __restrict__ u32, const float* __restrict__ W32,
                      const __half* __restrict__ uh, const __half* __restrict__ Wh,
                      float* __restrict__ out)
{
    const int t    = threadIdx.x;
    const int lane = t & 63;
    const int wav  = t >> 6;             // 0..11
    const int oh   = lane & 1;
    const int pr   = lane >> 1;          // 0..31
    const int bg   = blockIdx.x;         // 0..127
    const int k    = blockIdx.y;         // 0..9
    const int b0   = 2 * bg;
    const int b1   = 2 * bg + 1;

    __shared__ unsigned uhS2[2][8][S4];      // 73856 B  [b][o-pair row][col n]
    __shared__ unsigned cSu[2][Nn / 2];      // 4608 B   [b] e per n (half), uint-paired
    __shared__ float    redS[2][2][NW][18];  // 3456 B   [buf][b][wav][s0..15, d, m_w]
    // total exactly 81920 B -> 2 blocks/CU (24 waves) iff VGPR <= 85

    // ---------------- Phase 1: u_hat = u . W for BOTH b's, W loaded once ----------------
    #pragma unroll
    for (int rr = 0; rr < 3; ++rr) {
        const int n = 96 * wav + 32 * rr + pr;
        float a0[8], a1[8];
        #pragma unroll
        for (int o = 0; o < 8; ++o) { a0[o] = 0.f; a1[o] = 0.f; }
        if (HALF) {
            const uint4 uq0 = *(const uint4*)(uh + ((size_t)b0 * Nn + n) * 8);
            const uint4 uq1 = *(const uint4*)(uh + ((size_t)b1 * Nn + n) * 8);
            const unsigned uw0[4] = {uq0.x, uq0.y, uq0.z, uq0.w};
            const unsigned uw1[4] = {uq1.x, uq1.y, uq1.z, uq1.w};
            const __half* wbase = Wh + ((size_t)(k * Nn + n)) * 128 + oh * 8;
            #pragma unroll
            for (int p = 0; p < 4; ++p) {
                const uint4 qa = *(const uint4*)(wbase + (2 * p    ) * 16);
                const uint4 qb = *(const uint4*)(wbase + (2 * p + 1) * 16);
                const unsigned aw[4] = {qa.x, qa.y, qa.z, qa.w};
                const unsigned bw[4] = {qb.x, qb.y, qb.z, qb.w};
                #pragma unroll
                for (int jj = 0; jj < 4; ++jj) {
                    const unsigned wl  = __builtin_amdgcn_perm(aw[jj], bw[jj], PERM_LO);
                    const unsigned wh2 = __builtin_amdgcn_perm(aw[jj], bw[jj], PERM_HI);
                    a0[2*jj]   = fdot2u(wl,  uw0[p], a0[2*jj]);
                    a0[2*jj+1] = fdot2u(wh2, uw0[p], a0[2*jj+1]);
                    a1[2*jj]   = fdot2u(wl,  uw1[p], a1[2*jj]);
                    a1[2*jj+1] = fdot2u(wh2, uw1[p], a1[2*jj+1]);
                }
            }
        } else {
            float ua0[8], ua1[8];
            const float4* up0 = (const float4*)(u32 + ((size_t)b0 * Nn + n) * 8);
            const float4* up1 = (const float4*)(u32 + ((size_t)b1 * Nn + n) * 8);
            const float4 x0 = up0[0], x1 = up0[1];
            const float4 y0 = up1[0], y1 = up1[1];
            ua0[0]=x0.x; ua0[1]=x0.y; ua0[2]=x0.z; ua0[3]=x0.w;
            ua0[4]=x1.x; ua0[5]=x1.y; ua0[6]=x1.z; ua0[7]=x1.w;
            ua1[0]=y0.x; ua1[1]=y0.y; ua1[2]=y0.z; ua1[3]=y0.w;
            ua1[4]=y1.x; ua1[5]=y1.y; ua1[6]=y1.z; ua1[7]=y1.w;
            #pragma unroll
            for (int i = 0; i < 8; ++i) {
                const float4* wp = (const float4*)(W32 + ((size_t)k * Nn + n) * 128) + oh * 2 + i * 4;
                const float4 w0 = wp[0], w1 = wp[1];
                float wv[8];
                wv[0]=w0.x; wv[1]=w0.y; wv[2]=w0.z; wv[3]=w0.w;
                wv[4]=w1.x; wv[5]=w1.y; wv[6]=w1.z; wv[7]=w1.w;
                const float x = ua0[i], y = ua1[i];
                #pragma unroll
                for (int o = 0; o < 8; ++o) { a0[o] += x * wv[o]; a1[o] += y * wv[o]; }
            }
        }
        #pragma unroll
        for (int jj = 0; jj < 4; ++jj) {
            uhS2[0][oh * 4 + jj][n] = pkh2(a0[2*jj], a0[2*jj+1]);
            uhS2[1][oh * 4 + jj][n] = pkh2(a1[2*jj], a1[2*jj+1]);
        }
    }
    wave_lds_fence();   // each wave's scans read only its own 96-row region

    // ---------------- Phase 2: routing (lane parity = which b it routes) ----------------
    float lg[3] = {0.f, 0.f, 0.f};   // logits for this lane's b (= oh) rows
    unsigned vhsel[8];               // v for b = oh, packed half2 (all 8 o-pairs)
    const int j_s = lane & 7;
    const int g_s = lane >> 3;

    #pragma unroll
    for (int it = 0; it < 3; ++it) {
        float m_w = 0.f;
        if (it > 0) {
            // ---- a-scan: lane routes its b over its pair's 3 rows (LDS full-o reads) ----
            #pragma unroll
            for (int rr = 0; rr < 3; ++rr) {
                const int n = 96 * wav + 32 * rr + pr;
                float acc = 0.f;
                #pragma unroll
                for (int jj = 0; jj < 8; ++jj)
                    acc = fdot2u(uhS2[oh][jj][n], vhsel[jj], acc);
                lg[rr] += acc;
            }
            // ---- per-wave per-b max: parity-preserving reduce (offsets 2..32) ----
            float m = fmaxf(fmaxf(lg[0], lg[1]), lg[2]);
            #pragma unroll
            for (int off = 2; off <= 32; off <<= 1)
                m = fmaxf(m, __shfl_xor(m, off));
            m_w = m;                 // even lanes: m_b0; odd lanes: m_b1
            // ---- e -> cSu[oh] (wave-local; e <= 1, fp16-safe) ----
            #pragma unroll
            for (int rr = 0; rr < 3; ++rr) {
                const int n = 96 * wav + 32 * rr + pr;
                ((__half*)cSu[oh])[n] = __float2half(__expf(lg[rr] - m_w));
            }
            wave_lds_fence();        // readers are this same wave
        }

        // ---- s-scan: BOTH b's over wave's 96 rows, pairs (n0, n0+1) ----
        float2 sp0 = {0.f, 0.f}, sp1 = {0.f, 0.f};
        float dp0 = 0.f, dp1 = 0.f;
        #pragma unroll
        for (int cc = 0; cc < 6; ++cc) {
            const int n0 = 96 * wav + 2 * (g_s + 8 * cc);
            unsigned cp0, cp1;
            if (it == 0) { cp0 = ONE2; cp1 = ONE2; }
            else { cp0 = cSu[0][n0 >> 1]; cp1 = cSu[1][n0 >> 1]; }
            const uint2 q0 = *(const uint2*)&uhS2[0][j_s][n0];
            const uint2 q1 = *(const uint2*)&uhS2[1][j_s][n0];
            const unsigned px0 = __builtin_amdgcn_perm(q0.x, q0.y, PERM_LO);
            const unsigned py0 = __builtin_amdgcn_perm(q0.x, q0.y, PERM_HI);
            const unsigned px1 = __builtin_amdgcn_perm(q1.x, q1.y, PERM_LO);
            const unsigned py1 = __builtin_amdgcn_perm(q1.x, q1.y, PERM_HI);
            sp0.x = fdot2u(px0, cp0, sp0.x);
            sp0.y = fdot2u(py0, cp0, sp0.y);
            sp1.x = fdot2u(px1, cp1, sp1.x);
            sp1.y = fdot2u(py1, cp1, sp1.y);
            dp0   = fdot2u(cp0, ONE2, dp0);
            dp1   = fdot2u(cp1, ONE2, dp1);
        }
        #pragma unroll
        for (int off = 8; off <= 32; off <<= 1) {
            sp0.x += __shfl_xor(sp0.x, off);
            sp0.y += __shfl_xor(sp0.y, off);
            sp1.x += __shfl_xor(sp1.x, off);
            sp1.y += __shfl_xor(sp1.y, off);
            dp0   += __shfl_xor(dp0,   off);
            dp1   += __shfl_xor(dp1,   off);
        }
        const int buf = it & 1;
        if (lane < 8) {
            redS[buf][0][wav][2 * j_s    ] = sp0.x;
            redS[buf][0][wav][2 * j_s + 1] = sp0.y;
            redS[buf][1][wav][2 * j_s    ] = sp1.x;
            redS[buf][1][wav][2 * j_s + 1] = sp1.y;
        }
        if (lane == 0)
            *(float2*)&redS[buf][0][wav][16] = make_float2(dp0, m_w);  // m_w = m_b0 here
        if (lane == 1)
            *(float2*)&redS[buf][1][wav][16] = make_float2(dp1, m_w);  // m_w = m_b1 here
        __syncthreads();                               // the ONLY barrier per iter

        // ---- finalize: per-b cross-wave rescale + squash (redundant per wave) ----
        if (it < 2 || wav == 0) {
            const int bsel = (lane >> 4) & 1;
            const int o    = lane & 15;
            float M = redS[buf][bsel][0][17];
            #pragma unroll
            for (int w = 1; w < NW; ++w) M = fmaxf(M, redS[buf][bsel][w][17]);
            float s = 0.f, d = 0.f;
            #pragma unroll
            for (int w = 0; w < NW; ++w) {
                const float2 dm = *(const float2*)&redS[buf][bsel][w][16];
                const float sc = (it == 0) ? 1.f : __expf(dm.y - M);
                s += sc * redS[buf][bsel][w][o];
                d += sc * dm.x;
            }
            s /= d;
            float s2 = s * s;
            #pragma unroll
            for (int off = 1; off <= 8; off <<= 1) s2 += __shfl_xor(s2, off);
            const float scale = (s2 / (1.f + s2)) * rsqrtf(fmaxf(s2, 1e-30f));
            const float v = s * scale;
            if (it == 2) {
                if (wav == 0 && lane < 32)
                    out[((size_t)k * Bsz + b0 + bsel) * 16 + o] = v;
            } else {
                // lane's own b half: v_b0 in lanes 0-15, v_b1 in lanes 16-31.
                // runtime shfl lane index ok; array subscript jj static.
                #pragma unroll
                for (int jj = 0; jj < 8; ++jj)
                    vhsel[jj] = pkh2(__shfl(v, 16 * oh + 2 * jj),
                                     __shfl(v, 16 * oh + 2 * jj + 1));
            }
        }
    }
}

extern "C" void kernel_launch(void* const* d_in, const int* in_sizes, int n_in,
                              void* d_out, int out_size, void* d_ws, size_t ws_size,
                              hipStream_t stream) {
    const float* u = (const float*)d_in[0];
    const float* W = (const float*)d_in[1];
    float* out = (float*)d_out;
    const size_t need = (size_t)(W_ELEMS + U_ELEMS) * sizeof(__half);
    if (ws_size >= need) {
        __half* Wh = (__half*)d_ws;
        __half* uh = (__half*)((char*)d_ws + (size_t)W_ELEMS * sizeof(__half));
        cvt_kernel<<<dim3((W_ELEMS + U_ELEMS) / 8 / 256), dim3(256), 0, stream>>>(
            W, u, (__half2*)Wh, (__half2*)uh);
        digitcaps_kernel<true><<<dim3(128, 10), dim3(NT), 0, stream>>>(
            nullptr, nullptr, uh, Wh, out);
    } else {
        digitcaps_kernel<false><<<dim3(128, 10), dim3(NT), 0, stream>>>(
            u, W, nullptr, nullptr, out);
    }
}